// Round 8
// baseline (452.950 us; speedup 1.0000x reference)
//
#include <hip/hip_runtime.h>
#include <hip/hip_bf16.h>
#include <stdint.h>

// Problem constants
#define B_ 64
#define T_ 512
#define H_ 256
#define D_ 512
#define MS_ 64
#define ML_ 8
#define NST_ 64

typedef unsigned short u16;
typedef unsigned int u32;
typedef __bf16 bf8 __attribute__((ext_vector_type(8)));
typedef float f4 __attribute__((ext_vector_type(4)));

__device__ __forceinline__ u16 f2bf(float f) {
    u32 u = __builtin_bit_cast(u32, f);
    u += 0x7fffu + ((u >> 16) & 1u);   // round-to-nearest-even
    return (u16)(u >> 16);
}
__device__ __forceinline__ float sigm(float x) { return 1.f / (1.f + __expf(-x)); }

// ---------------- weight packing ----------------
// wc[dir][gate(1024)][k(768)]: k<256 -> W_hh[gate][k], k>=256 -> W_ih[gate][k-256]
__global__ __launch_bounds__(256) void build_wc(const float* __restrict__ wihf,
                                                const float* __restrict__ whhf,
                                                const float* __restrict__ wihb,
                                                const float* __restrict__ whhb,
                                                u16* __restrict__ wc) {
    int i = blockIdx.x * 256 + threadIdx.x;
    if (i >= 2 * 1024 * 768) return;
    int dir = i / (1024 * 768);
    int rem = i - dir * 1024 * 768;
    int g = rem / 768;
    int k = rem - g * 768;
    const float* wih = dir ? wihb : wihf;
    const float* whh = dir ? whhb : whhf;
    float v = (k < 256) ? whh[g * 256 + k] : wih[g * 512 + (k - 256)];
    wc[i] = f2bf(v);
}

__global__ __launch_bounds__(256) void zero_ws(uint4* __restrict__ dst, int n4) {
    int i = blockIdx.x * 256 + threadIdx.x;
    if (i < n4) { uint4 z = {0u, 0u, 0u, 0u}; dst[i] = z; }
}

// ---------------- span packing (parallel, 1 block/row, 1 thread/token) -------
__global__ __launch_bounds__(512) void pack_spans2(const int* __restrict__ bio,
                                                   int* __restrict__ tok,
                                                   int* __restrict__ lenb) {
    __shared__ int wsum[8];
    __shared__ int start_s[64];
    __shared__ int len_s[64];
    int b = blockIdx.x;
    int t = threadIdx.x;
    int lane = t & 63, w = t >> 6;
    int v = bio[b * T_ + t];
    int bm = (v == 1);
    int im = (v == 2);
    if (t < 64) len_s[t] = 0;

    int x = bm;
#pragma unroll
    for (int off = 1; off < 64; off <<= 1) {
        int y = __shfl_up(x, off, 64);
        if (lane >= off) x += y;
    }
    if (lane == 63) wsum[w] = x;
    __syncthreads();
    int wof = 0;
    for (int i = 0; i < w; ++i) wof += wsum[i];
    int sid = x + wof - 1;
    int valid = ((bm | im) && sid >= 0) ? 1 : 0;
    __syncthreads();

    x = valid;
#pragma unroll
    for (int off = 1; off < 64; off <<= 1) {
        int y = __shfl_up(x, off, 64);
        if (lane >= off) x += y;
    }
    if (lane == 63) wsum[w] = x;
    __syncthreads();
    wof = 0;
    for (int i = 0; i < w; ++i) wof += wsum[i];
    int cs = x + wof;

    if (bm && sid < MS_) start_s[sid] = cs;
    __syncthreads();

    if (valid && sid < MS_) {
        int rank = cs - start_s[sid];
        if (rank < ML_) {
            tok[(b * MS_ + sid) * ML_ + rank] = t;
            atomicAdd(&len_s[sid], 1);
        }
    }
    __syncthreads();
    if (t < 64) lenb[b * MS_ + t] = len_s[t];
}

// ---------------- per-step active lists: one block per step p ----------------
__global__ __launch_bounds__(256) void build_lists8(const int* __restrict__ lenb,
                                                    int* __restrict__ lists,
                                                    int* __restrict__ counts) {
    __shared__ int wsum[4];
    int p = blockIdx.x;
    int tid = threadIdx.x;
    int lane = tid & 63, w = tid >> 6;
    int len[16];
#pragma unroll
    for (int i = 0; i < 16; ++i) len[i] = lenb[tid * 16 + i];
    int c = 0;
#pragma unroll
    for (int i = 0; i < 16; ++i) c += (len[i] > p) ? 1 : 0;
    int x = c;
#pragma unroll
    for (int off = 1; off < 64; off <<= 1) {
        int y = __shfl_up(x, off, 64);
        if (lane >= off) x += y;
    }
    if (lane == 63) wsum[w] = x;
    __syncthreads();
    int wof = 0;
    for (int i = 0; i < w; ++i) wof += wsum[i];
    int pos = wof + x - c;
#pragma unroll
    for (int i = 0; i < 16; ++i)
        if (len[i] > p) lists[p * 4096 + pos++] = tid * 16 + i;
    if (tid == 255) counts[p] = pos;
}

// ---------------- LSTM step: K=768 GEMM ([h|x]) + fused cell epilogue --------
// Grid (hb=4, span-block=64, dir=2). Block: M=64 active spans, K=768,
// N=256 = 4 gate-types x 64-hidden chunk (hb). C-layout puts I,F,G,O of a
// (span,hidden) in-lane -> cell math in epilogue. x gathered+converted from
// lstm_repr (f32) during A-staging; each (span,rank,dir) row read exactly once.
// p==0: skip h k-tiles (h=0) and the c-state read -> no zero-init needed.
__global__ __launch_bounds__(256) void lstm_step2(const u16* __restrict__ wc,
                                                  const float* __restrict__ repr,
                                                  const int* __restrict__ tok,
                                                  const int* __restrict__ lenb,
                                                  const int* __restrict__ lists,
                                                  const int* __restrict__ counts,
                                                  const float* __restrict__ b_f,
                                                  const float* __restrict__ b_b,
                                                  const u16* __restrict__ hread,
                                                  u16* __restrict__ hwrite,
                                                  float* __restrict__ cst,
                                                  float* __restrict__ pooled,
                                                  int p) {
    int cnt = counts[p];
    int base = blockIdx.y * 64;
    if (base >= cnt) return;
    int hb = blockIdx.x;
    int dir = blockIdx.z;

    __shared__ u16 As[64 * 72];
    __shared__ u16 Bs[256 * 72];
    __shared__ int sp_s[64], ln_s[64];
    __shared__ u32 xb_s[64];
    __shared__ float bias_s[256];
    int tid = threadIdx.x;
    if (tid < 64) {
        int s = -1, l = 0; u32 xo = 0;
        if (base + tid < cnt) {
            s = lists[p * 4096 + base + tid];
            l = lenb[s];
            int rk = dir ? (l - 1 - p) : p;
            int t = tok[s * ML_ + rk];
            int b = s >> 6;
            xo = (u32)(b * T_ + t) * D_;
        }
        sp_s[tid] = s; ln_s[tid] = l; xb_s[tid] = xo;
    }
    {
        const float* bias = dir ? b_b : b_f;
        bias_s[tid] = bias[(tid >> 6) * 256 + hb * 64 + (tid & 63)];
    }
    __syncthreads();

    int lane = tid & 63, wv = tid >> 6;
    int mr = lane & 15, q = lane >> 4, q8 = q * 8;
    int w16 = wv * 16;
    const u16* wbase = wc + (size_t)dir * 1024 * 768;

    f4 acc[4][4];            // [gate-type][n-subtile]
    f4 zed = {0.f, 0.f, 0.f, 0.f};
#pragma unroll
    for (int i = 0; i < 4; ++i)
#pragma unroll
        for (int j = 0; j < 4; ++j) acc[i][j] = zed;

    int ktStart = (p == 0) ? 4 : 0;
    for (int kt = ktStart; kt < 12; ++kt) {
        // stage A: 64 spans x 64 k-cols. kt<4: h (bf16); kt>=4: x (f32 -> bf16)
#pragma unroll
        for (int i = 0; i < 2; ++i) {
            int cch = tid + i * 256;
            int row = cch >> 3, cc = (cch & 7) * 8;
            int s = sp_s[row];
            if (kt < 4) {
                uint4 v = {0u, 0u, 0u, 0u};
                if (s >= 0) v = *(const uint4*)(hread + ((size_t)dir * 4096 + s) * 256 + kt * 64 + cc);
                *(uint4*)&As[row * 72 + cc] = v;
            } else {
                ushort4 o0 = {0, 0, 0, 0}, o1 = {0, 0, 0, 0};
                if (s >= 0) {
                    const float4* xp = (const float4*)(repr + xb_s[row] + (kt - 4) * 64 + cc);
                    float4 a0 = xp[0], a1 = xp[1];
                    o0.x = f2bf(a0.x); o0.y = f2bf(a0.y); o0.z = f2bf(a0.z); o0.w = f2bf(a0.w);
                    o1.x = f2bf(a1.x); o1.y = f2bf(a1.y); o1.z = f2bf(a1.z); o1.w = f2bf(a1.w);
                }
                *(ushort4*)&As[row * 72 + cc] = o0;
                *(ushort4*)&As[row * 72 + cc + 4] = o1;
            }
        }
        // stage B: 256 gate rows (4 types x 64-hid chunk), k-chunk 64 (8/thread)
#pragma unroll
        for (int i = 0; i < 8; ++i) {
            int cch = tid + i * 256;
            int row = cch >> 3, cc = (cch & 7) * 8;
            int wrow = (row >> 6) * 256 + hb * 64 + (row & 63);
            uint4 v = *(const uint4*)(wbase + (size_t)wrow * 768 + kt * 64 + cc);
            *(uint4*)&Bs[row * 72 + cc] = v;
        }
        __syncthreads();
#pragma unroll
        for (int kk = 0; kk < 64; kk += 32) {
            bf8 af = *(const bf8*)&As[(w16 + mr) * 72 + kk + q8];
#pragma unroll
            for (int gt = 0; gt < 4; ++gt)
#pragma unroll
                for (int ns = 0; ns < 4; ++ns) {
                    bf8 bg = *(const bf8*)&Bs[(gt * 64 + ns * 16 + mr) * 72 + kk + q8];
                    acc[gt][ns] = __builtin_amdgcn_mfma_f32_16x16x32_bf16(af, bg, acc[gt][ns], 0, 0, 0);
                }
        }
        __syncthreads();
    }

    // epilogue: cell update. lane holds I,F,G,O for span m = w16+q*4+r,
    // hid = hb*64 + ns*16 + mr.
#pragma unroll
    for (int ns = 0; ns < 4; ++ns)
#pragma unroll
        for (int r = 0; r < 4; ++r) {
            int m = w16 + q * 4 + r;
            int s = sp_s[m];
            if (s < 0) continue;
            int lidx = ns * 16 + mr;
            int hid = hb * 64 + lidx;
            float I = acc[0][ns][r] + bias_s[lidx];
            float F = acc[1][ns][r] + bias_s[64 + lidx];
            float G = acc[2][ns][r] + bias_s[128 + lidx];
            float O = acc[3][ns][r] + bias_s[192 + lidx];
            size_t ci = ((size_t)dir * 4096 + s) * 256 + hid;
            float c0 = (p == 0) ? 0.f : cst[ci];
            float cn = sigm(F) * c0 + sigm(I) * tanhf(G);
            cst[ci] = cn;
            float h = sigm(O) * tanhf(cn);
            hwrite[ci] = f2bf(h);
            pooled[(size_t)s * 512 + dir * 256 + hid] += h;
        }
}

// ---------------- final scores: MFMA GEMM [4096x512] x [512x64] ----------------
__global__ __launch_bounds__(256) void scores_mfma(const float* __restrict__ pooled,
                                                   const float* __restrict__ emb,
                                                   float* __restrict__ out) {
    int g = blockIdx.x;
    int tid = threadIdx.x;
    __shared__ u16 As[64 * 72];
    __shared__ u16 Bs[64 * 72];
    int lane = tid & 63;
    int w16 = (tid >> 6) * 16;
    int mr = lane & 15;
    int q = lane >> 4;
    int q8 = q * 8;

    f4 acc[4];
    f4 zed = {0.f, 0.f, 0.f, 0.f};
#pragma unroll
    for (int i = 0; i < 4; ++i) acc[i] = zed;

    for (int kt = 0; kt < 8; ++kt) {
#pragma unroll
        for (int i = 0; i < 2; ++i) {
            int cch = tid + i * 256;
            int row = cch >> 3;
            int cc = (cch & 7) * 8;
            const float4* a = (const float4*)(pooled + (size_t)(g * 64 + row) * 512 + kt * 64 + cc);
            float4 v0 = a[0], v1 = a[1];
            ushort4 o0, o1;
            o0.x = f2bf(v0.x); o0.y = f2bf(v0.y); o0.z = f2bf(v0.z); o0.w = f2bf(v0.w);
            o1.x = f2bf(v1.x); o1.y = f2bf(v1.y); o1.z = f2bf(v1.z); o1.w = f2bf(v1.w);
            *(ushort4*)&As[row * 72 + cc] = o0;
            *(ushort4*)&As[row * 72 + cc + 4] = o1;
            const float4* b = (const float4*)(emb + (size_t)row * 512 + kt * 64 + cc);
            float4 w0 = b[0], w1 = b[1];
            ushort4 p0, p1;
            p0.x = f2bf(w0.x); p0.y = f2bf(w0.y); p0.z = f2bf(w0.z); p0.w = f2bf(w0.w);
            p1.x = f2bf(w1.x); p1.y = f2bf(w1.y); p1.z = f2bf(w1.z); p1.w = f2bf(w1.w);
            *(ushort4*)&Bs[row * 72 + cc] = p0;
            *(ushort4*)&Bs[row * 72 + cc + 4] = p1;
        }
        __syncthreads();
#pragma unroll
        for (int kk = 0; kk < 64; kk += 32) {
            bf8 af = *(const bf8*)&As[(w16 + mr) * 72 + kk + q8];
#pragma unroll
            for (int nt = 0; nt < 4; ++nt) {
                bf8 bgv = *(const bf8*)&Bs[(nt * 16 + mr) * 72 + kk + q8];
                acc[nt] = __builtin_amdgcn_mfma_f32_16x16x32_bf16(af, bgv, acc[nt], 0, 0, 0);
            }
        }
        __syncthreads();
    }
#pragma unroll
    for (int nt = 0; nt < 4; ++nt)
#pragma unroll
        for (int r = 0; r < 4; ++r) {
            int m = g * 64 + w16 + q * 4 + r;
            int n = nt * 16 + mr;
            out[(size_t)m * 64 + n] = acc[nt][r];
        }
}

// ---------------- launch ----------------

extern "C" void kernel_launch(void* const* d_in, const int* in_sizes, int n_in,
                              void* d_out, int out_size, void* d_ws, size_t ws_size,
                              hipStream_t stream) {
    const float* lstm_repr = (const float*)d_in[0];
    const float* W_ih_f = (const float*)d_in[1];
    const float* W_hh_f = (const float*)d_in[2];
    const float* b_f    = (const float*)d_in[3];
    const float* W_ih_b = (const float*)d_in[4];
    const float* W_hh_b = (const float*)d_in[5];
    const float* b_b    = (const float*)d_in[6];
    const float* slot_emb = (const float*)d_in[7];
    const int* bio      = (const int*)d_in[8];
    float* out = (float*)d_out;

    char* ws = (char*)d_ws;
    u16*  wc     = (u16*)(ws + 0);              // 2*1024*768 bf16    = 3,145,728
    int*  tok    = (int*)(ws + 3145728);        // 4096*8 i32         =   131,072
    int*  lenb   = (int*)(ws + 3276800);        // 4096 i32           =    16,384
    int*  lists  = (int*)(ws + 3293184);        // 8*4096 i32         =   131,072
    int*  counts = (int*)(ws + 3424256);        // 8 i32 (pad 256)
    u16*  hbuf   = (u16*)(ws + 3424512);        // 2par*2dir*4096*256 = 8,388,608
    float* cst   = (float*)(ws + 11813120);     // 2*4096*256 f32     = 8,388,608
    float* pooled= (float*)(ws + 20201728);     // 4096*512 f32       = 8,388,608 (zeroed)
    // total: 28,590,336 bytes

    build_wc<<<6144, 256, 0, stream>>>(W_ih_f, W_hh_f, W_ih_b, W_hh_b, wc);
    pack_spans2<<<64, 512, 0, stream>>>(bio, tok, lenb);
    build_lists8<<<8, 256, 0, stream>>>(lenb, lists, counts);
    zero_ws<<<2048, 256, 0, stream>>>((uint4*)pooled, 524288);

    const size_t HPAR = (size_t)2 * 4096 * 256;   // elements per parity
    for (int p = 0; p < 8; ++p) {
        u16* hr = hbuf + (size_t)(p & 1) * HPAR;
        u16* hw = hbuf + (size_t)((p & 1) ^ 1) * HPAR;
        lstm_step2<<<dim3(4, 64, 2), 256, 0, stream>>>(wc, lstm_repr, tok, lenb,
                                                       lists, counts, b_f, b_b,
                                                       hr, hw, cst, pooled, p);
    }
    scores_mfma<<<64, 256, 0, stream>>>(pooled, slot_emb, out);
}